// Round 1
// baseline (3894.905 us; speedup 1.0000x reference)
//
#include <hip/hip_runtime.h>

#define DPDIM 32         // path/link state dim
#define GCOLS 96         // 3*DPDIM gate columns
#define PLEN 8
#define T_ITERS 8
#define RUNITS 256

// ---------------- fast activations (v_exp_f32 + v_rcp_f32) ----------------
__device__ __forceinline__ float fast_sigmoid(float a) {
    return __builtin_amdgcn_rcpf(1.0f + __expf(-a));
}
__device__ __forceinline__ float fast_tanh(float a) {
    // tanh(x) = 1 - 2/(1+e^{2x}); stable at both infinities
    return 1.0f - 2.0f * __builtin_amdgcn_rcpf(1.0f + __expf(2.0f * a));
}

#define ACC4(a0,a1,a2,a3, s, V) \
    a0 = fmaf((s), (V).x, a0); a1 = fmaf((s), (V).y, a1); \
    a2 = fmaf((s), (V).z, a2); a3 = fmaf((s), (V).w, a3);

// ---------------- GRU step (Keras reset_after): one thread = one row -------
// h[32] in regs (old state, statically indexed), x[32] in regs.
// Gate outputs go through per-thread LDS column hl (stride STRIDE) so the
// jb-loop can stay dynamic (small I-footprint). On exit h[] = new state and
// hl holds the same values.
template<int STRIDE>
__device__ __forceinline__ void gru_step(
    float* __restrict__ h, const float* __restrict__ x,
    const float* __restrict__ sW, const float* __restrict__ sU,
    const float* __restrict__ sbi, const float* __restrict__ sbh,
    float* __restrict__ hl)
{
    for (int jb = 0; jb < 8; ++jb) {
        float az0=0.f,az1=0.f,az2=0.f,az3=0.f;
        float ar0=0.f,ar1=0.f,ar2=0.f,ar3=0.f;
        float ai0=0.f,ai1=0.f,ai2=0.f,ai3=0.f;
        float ah0=0.f,ah1=0.f,ah2=0.f,ah3=0.f;
        const float* wp = sW + jb*4;
        const float* up = sU + jb*4;
        #pragma unroll
        for (int k = 0; k < DPDIM; ++k) {
            const float xk = x[k], hk = h[k];
            const float4 WZ = *(const float4*)(wp + k*GCOLS);
            const float4 WR = *(const float4*)(wp + k*GCOLS + 32);
            const float4 WH = *(const float4*)(wp + k*GCOLS + 64);
            const float4 UZ = *(const float4*)(up + k*GCOLS);
            const float4 UR = *(const float4*)(up + k*GCOLS + 32);
            const float4 UH = *(const float4*)(up + k*GCOLS + 64);
            ACC4(az0,az1,az2,az3, xk, WZ); ACC4(az0,az1,az2,az3, hk, UZ);
            ACC4(ar0,ar1,ar2,ar3, xk, WR); ACC4(ar0,ar1,ar2,ar3, hk, UR);
            ACC4(ai0,ai1,ai2,ai3, xk, WH);
            ACC4(ah0,ah1,ah2,ah3, hk, UH);
        }
        const float4 BZI = *(const float4*)(sbi + jb*4);
        const float4 BRI = *(const float4*)(sbi + 32 + jb*4);
        const float4 BHI = *(const float4*)(sbi + 64 + jb*4);
        const float4 BZH = *(const float4*)(sbh + jb*4);
        const float4 BRH = *(const float4*)(sbh + 32 + jb*4);
        const float4 BHH = *(const float4*)(sbh + 64 + jb*4);
        float* hq = hl + (jb*4)*STRIDE;
        {
            float z = fast_sigmoid(az0 + BZI.x + BZH.x);
            float r = fast_sigmoid(ar0 + BRI.x + BRH.x);
            float c = fast_tanh(ai0 + BHI.x + r * (ah0 + BHH.x));
            float ho = hq[0*STRIDE]; hq[0*STRIDE] = z*ho + (1.f - z)*c;
        }
        {
            float z = fast_sigmoid(az1 + BZI.y + BZH.y);
            float r = fast_sigmoid(ar1 + BRI.y + BRH.y);
            float c = fast_tanh(ai1 + BHI.y + r * (ah1 + BHH.y));
            float ho = hq[1*STRIDE]; hq[1*STRIDE] = z*ho + (1.f - z)*c;
        }
        {
            float z = fast_sigmoid(az2 + BZI.z + BZH.z);
            float r = fast_sigmoid(ar2 + BRI.z + BRH.z);
            float c = fast_tanh(ai2 + BHI.z + r * (ah2 + BHH.z));
            float ho = hq[2*STRIDE]; hq[2*STRIDE] = z*ho + (1.f - z)*c;
        }
        {
            float z = fast_sigmoid(az3 + BZI.w + BZH.w);
            float r = fast_sigmoid(ar3 + BRI.w + BRH.w);
            float c = fast_tanh(ai3 + BHI.w + r * (ah3 + BHH.w));
            float ho = hq[3*STRIDE]; hq[3*STRIDE] = z*ho + (1.f - z)*c;
        }
    }
    #pragma unroll
    for (int j = 0; j < DPDIM; ++j) h[j] = hl[j*STRIDE];
}

// ---------------- init states ----------------
__global__ __launch_bounds__(256) void init_kernel(
    const float* __restrict__ traffic, const float* __restrict__ packets,
    const float* __restrict__ eqlam, const float* __restrict__ avgpkt,
    const float* __restrict__ capacity, const float* __restrict__ queues,
    float* __restrict__ path_state, float* __restrict__ link_state,
    int n_paths, int n_links)
{
    int i = blockIdx.x * 256 + threadIdx.x;
    if (i < n_paths) {
        float4* row = (float4*)(path_state + (size_t)i * DPDIM);
        row[0] = make_float4(traffic[i], packets[i], eqlam[i], avgpkt[i]);
        float4 z = make_float4(0.f, 0.f, 0.f, 0.f);
        #pragma unroll
        for (int k = 1; k < 8; ++k) row[k] = z;
    }
    if (i < n_links) {
        float4* row = (float4*)(link_state + (size_t)i * DPDIM);
        row[0] = make_float4(capacity[i], queues[i], 0.f, 0.f);
        float4 z = make_float4(0.f, 0.f, 0.f, 0.f);
        #pragma unroll
        for (int k = 1; k < 8; ++k) row[k] = z;
    }
}

// ---------------- CSR build ----------------
__global__ __launch_bounds__(256) void zero_counts_kernel(int* __restrict__ counts, int n) {
    int i = blockIdx.x * 256 + threadIdx.x;
    if (i < n) counts[i] = 0;
}
__global__ __launch_bounds__(256) void hist_kernel(
    const int* __restrict__ link_to_path, int* __restrict__ counts, int n) {
    int i = blockIdx.x * 256 + threadIdx.x;
    if (i < n) atomicAdd(&counts[link_to_path[i]], 1);
}
__global__ __launch_bounds__(1024) void scan_kernel(
    const int* __restrict__ counts, int* __restrict__ offsets,
    int* __restrict__ cursor, int n)
{
    __shared__ int s[1024];
    int t = threadIdx.x;
    int chunk = (n + 1023) >> 10;
    int lo = t * chunk;
    int hi = lo + chunk; if (hi > n) hi = n;
    int local = 0;
    for (int i = lo; i < hi; ++i) local += counts[i];
    s[t] = local;
    __syncthreads();
    for (int d = 1; d < 1024; d <<= 1) {
        int v = (t >= d) ? s[t - d] : 0;
        __syncthreads();
        s[t] += v;
        __syncthreads();
    }
    int base = (t > 0) ? s[t - 1] : 0;
    for (int i = lo; i < hi; ++i) {
        offsets[i] = base; cursor[i] = base; base += counts[i];
    }
    if (t == 1023) offsets[n] = s[1023];
}
__global__ __launch_bounds__(256) void fill_kernel(
    const int* __restrict__ link_to_path, int* __restrict__ cursor,
    int* __restrict__ entries, int n) {
    int e = blockIdx.x * 256 + threadIdx.x;
    if (e < n) {
        int l = link_to_path[e];
        int pos = atomicAdd(&cursor[l], 1);
        entries[pos] = e >> 3;   // path id (PLEN == 8)
    }
}

// ---------------- path GRU: 8 masked steps over the path's links -----------
__global__ __launch_bounds__(128, 1) void path_kernel(
    const float* __restrict__ link_state, float* __restrict__ path_state,
    const int* __restrict__ link_to_path,
    const float* __restrict__ Wp, const float* __restrict__ Up,
    const float* __restrict__ bip, const float* __restrict__ bhp, int n_paths)
{
    __shared__ __align__(16) float sW[DPDIM*GCOLS];
    __shared__ __align__(16) float sU[DPDIM*GCOLS];
    __shared__ __align__(16) float sbi[GCOLS];
    __shared__ __align__(16) float sbh[GCOLS];
    __shared__ float h_lds[DPDIM * 128];
    int t = threadIdx.x;
    for (int i = t; i < DPDIM*GCOLS; i += 128) { sW[i] = Wp[i]; sU[i] = Up[i]; }
    for (int i = t; i < GCOLS; i += 128)       { sbi[i] = bip[i]; sbh[i] = bhp[i]; }
    int p = blockIdx.x * 128 + t;
    bool active = p < n_paths;
    float h[DPDIM];
    if (active) {
        const float4* row = (const float4*)(path_state + (size_t)p * DPDIM);
        #pragma unroll
        for (int k = 0; k < 8; ++k) {
            float4 v = row[k];
            h[4*k+0]=v.x; h[4*k+1]=v.y; h[4*k+2]=v.z; h[4*k+3]=v.w;
        }
    } else {
        #pragma unroll
        for (int k = 0; k < DPDIM; ++k) h[k] = 0.f;
    }
    #pragma unroll
    for (int j = 0; j < DPDIM; ++j) h_lds[j*128 + t] = h[j];
    __syncthreads();

    for (int s = 0; s < PLEN; ++s) {
        int l = active ? link_to_path[p*PLEN + s] : 0;
        float x[DPDIM];
        bool nz = false;
        const float4* lrow = (const float4*)(link_state + (size_t)l * DPDIM);
        #pragma unroll
        for (int k = 0; k < 8; ++k) {
            float4 v = lrow[k];
            x[4*k+0]=v.x; x[4*k+1]=v.y; x[4*k+2]=v.z; x[4*k+3]=v.w;
            nz = nz || (v.x != 0.f) || (v.y != 0.f) || (v.z != 0.f) || (v.w != 0.f);
        }
        if (active && nz)
            gru_step<128>(h, x, sW, sU, sbi, sbh, &h_lds[t]);
    }
    if (active) {
        float4* row = (float4*)(path_state + (size_t)p * DPDIM);
        #pragma unroll
        for (int k = 0; k < 8; ++k)
            row[k] = make_float4(h[4*k+0], h[4*k+1], h[4*k+2], h[4*k+3]);
    }
}

// ---------------- segment sum: path states -> per-link sums ----------------
__global__ __launch_bounds__(256) void seg_sum_kernel(
    const float* __restrict__ path_state, const int* __restrict__ offsets,
    const int* __restrict__ entries, float* __restrict__ path_sum, int n_links)
{
    int t = threadIdx.x;
    int d = t & 31, li = t >> 5;        // 8 links per block, 32 dims each
    int l = blockIdx.x * 8 + li;
    if (l >= n_links) return;
    int beg = offsets[l], end = offsets[l+1];
    float acc = 0.f;
    for (int q = beg; q < end; ++q) {
        int p = entries[q];
        acc += path_state[(size_t)p * DPDIM + d];
    }
    path_sum[(size_t)l * DPDIM + d] = acc;
}

// ---------------- link GRU: one step, x = path_sum -------------------------
__global__ __launch_bounds__(128, 1) void link_kernel(
    const float* __restrict__ path_sum, float* __restrict__ link_state,
    const float* __restrict__ Wl, const float* __restrict__ Ul,
    const float* __restrict__ bil, const float* __restrict__ bhl, int n_links)
{
    __shared__ __align__(16) float sW[DPDIM*GCOLS];
    __shared__ __align__(16) float sU[DPDIM*GCOLS];
    __shared__ __align__(16) float sbi[GCOLS];
    __shared__ __align__(16) float sbh[GCOLS];
    __shared__ float h_lds[DPDIM * 128];
    int t = threadIdx.x;
    for (int i = t; i < DPDIM*GCOLS; i += 128) { sW[i] = Wl[i]; sU[i] = Ul[i]; }
    for (int i = t; i < GCOLS; i += 128)       { sbi[i] = bil[i]; sbh[i] = bhl[i]; }
    int l = blockIdx.x * 128 + t;
    bool active = l < n_links;
    float h[DPDIM], x[DPDIM];
    if (active) {
        const float4* hrow = (const float4*)(link_state + (size_t)l * DPDIM);
        const float4* xrow = (const float4*)(path_sum + (size_t)l * DPDIM);
        #pragma unroll
        for (int k = 0; k < 8; ++k) {
            float4 v = hrow[k];
            h[4*k+0]=v.x; h[4*k+1]=v.y; h[4*k+2]=v.z; h[4*k+3]=v.w;
            float4 u = xrow[k];
            x[4*k+0]=u.x; x[4*k+1]=u.y; x[4*k+2]=u.z; x[4*k+3]=u.w;
        }
    } else {
        #pragma unroll
        for (int k = 0; k < DPDIM; ++k) { h[k] = 0.f; x[k] = 0.f; }
    }
    #pragma unroll
    for (int j = 0; j < DPDIM; ++j) h_lds[j*128 + t] = h[j];
    __syncthreads();
    if (active) {
        gru_step<128>(h, x, sW, sU, sbi, sbh, &h_lds[t]);
        float4* row = (float4*)(link_state + (size_t)l * DPDIM);
        #pragma unroll
        for (int k = 0; k < 8; ++k)
            row[k] = make_float4(h[4*k+0], h[4*k+1], h[4*k+2], h[4*k+3]);
    }
}

// ---------------- readout: relu(ls@W1+b1) -> relu(@W2+b2) -> @W3+b3 --------
__global__ __launch_bounds__(256) void readout_kernel(
    const float* __restrict__ link_state,
    const float* __restrict__ W1, const float* __restrict__ b1,
    const float* __restrict__ W2, const float* __restrict__ b2,
    const float* __restrict__ W3, const float* __restrict__ b3,
    float* __restrict__ out, int n_links)
{
    __shared__ __align__(16) float s_ls[64*DPDIM];   // 8 KB
    __shared__ float s_m[64*257];                    // 64.25 KB (r1, then r2*w3)
    __shared__ float s_part[256];
    __shared__ float s_w3[RUNITS];
    int t = threadIdx.x;
    int l0 = blockIdx.x * 64;
    int nl = n_links - l0; if (nl > 64) nl = 64;
    for (int i = t; i < nl*DPDIM; i += 256) s_ls[i] = link_state[(size_t)l0*DPDIM + i];
    s_w3[t] = W3[t];
    __syncthreads();
    // r1 = relu(ls @ W1 + b1) ; thread t owns column t
    float w1c[DPDIM];
    #pragma unroll
    for (int k = 0; k < DPDIM; ++k) w1c[k] = W1[k*RUNITS + t];
    float b1t = b1[t];
    for (int i = 0; i < nl; ++i) {
        float a = b1t;
        #pragma unroll
        for (int k = 0; k < DPDIM; ++k) a = fmaf(s_ls[i*DPDIM + k], w1c[k], a);
        s_m[i*257 + t] = fmaxf(a, 0.f);
    }
    __syncthreads();
    // r2 accum: acc[i] = sum_k r1[i][k] * W2[k][t]   (broadcast LDS reads)
    float acc[64];
    #pragma unroll
    for (int i = 0; i < 64; ++i) acc[i] = 0.f;
    for (int k = 0; k < RUNITS; ++k) {
        float w = W2[k*RUNITS + t];
        #pragma unroll
        for (int i = 0; i < 64; ++i) acc[i] = fmaf(s_m[i*257 + k], w, acc[i]);
    }
    __syncthreads();
    // store relu(acc+b2)*w3 back into s_m
    float b2t = b2[t];
    #pragma unroll
    for (int i = 0; i < 64; ++i)
        s_m[i*257 + t] = fmaxf(acc[i] + b2t, 0.f) * s_w3[t];
    __syncthreads();
    // reduce 256 cols per link: thread t handles link i=t>>2, quarter q=t&3
    {
        int i = t >> 2, q = t & 3;
        float ssum = 0.f;
        for (int j = q*64; j < q*64 + 64; ++j) ssum += s_m[i*257 + j];
        s_part[t] = ssum;
    }
    __syncthreads();
    if (t < nl)
        out[l0 + t] = b3[0] + s_part[t*4] + s_part[t*4+1] + s_part[t*4+2] + s_part[t*4+3];
}

// ---------------- launch ----------------
extern "C" void kernel_launch(void* const* d_in, const int* in_sizes, int n_in,
                              void* d_out, int out_size, void* d_ws, size_t ws_size,
                              hipStream_t stream)
{
    const float* traffic  = (const float*)d_in[0];
    const float* packets  = (const float*)d_in[1];
    const float* eqlam    = (const float*)d_in[2];
    const float* avgpkt   = (const float*)d_in[3];
    const float* capacity = (const float*)d_in[4];
    const float* queues   = (const float*)d_in[5];
    const int* link_to_path = (const int*)d_in[6];
    const float* Wp  = (const float*)d_in[13];
    const float* Up  = (const float*)d_in[14];
    const float* bip = (const float*)d_in[15];
    const float* bhp = (const float*)d_in[16];
    const float* Wl  = (const float*)d_in[17];
    const float* Ul  = (const float*)d_in[18];
    const float* bil = (const float*)d_in[19];
    const float* bhl = (const float*)d_in[20];
    const float* W1  = (const float*)d_in[21];
    const float* b1  = (const float*)d_in[22];
    const float* W2  = (const float*)d_in[23];
    const float* b2  = (const float*)d_in[24];
    const float* W3  = (const float*)d_in[25];
    const float* b3  = (const float*)d_in[26];
    const int n_paths = in_sizes[0];     // 100000
    const int n_links = in_sizes[4];     // 20000
    const int n_ent   = in_sizes[6];     // 800000

    char* ws = (char*)d_ws;
    size_t off = 0;
    auto salloc = [&](size_t bytes) -> void* {
        void* p = ws + off;
        off += (bytes + 15) & ~size_t(15);
        return p;
    };
    float* path_state = (float*)salloc((size_t)n_paths * DPDIM * 4);
    float* link_state = (float*)salloc((size_t)n_links * DPDIM * 4);
    float* path_sum   = (float*)salloc((size_t)n_links * DPDIM * 4);
    int* counts  = (int*)salloc((size_t)n_links * 4);
    int* offsets = (int*)salloc((size_t)(n_links + 1) * 4);
    int* cursor  = (int*)salloc((size_t)n_links * 4);
    int* entries = (int*)salloc((size_t)n_ent * 4);
    (void)ws_size; (void)n_in; (void)out_size;

    int gmax = ( (n_paths > n_links ? n_paths : n_links) + 255 ) / 256;
    zero_counts_kernel<<<(n_links + 255)/256, 256, 0, stream>>>(counts, n_links);
    init_kernel<<<gmax, 256, 0, stream>>>(traffic, packets, eqlam, avgpkt,
                                          capacity, queues, path_state, link_state,
                                          n_paths, n_links);
    hist_kernel<<<(n_ent + 255)/256, 256, 0, stream>>>(link_to_path, counts, n_ent);
    scan_kernel<<<1, 1024, 0, stream>>>(counts, offsets, cursor, n_links);
    fill_kernel<<<(n_ent + 255)/256, 256, 0, stream>>>(link_to_path, cursor, entries, n_ent);

    for (int it = 0; it < T_ITERS; ++it) {
        path_kernel<<<(n_paths + 127)/128, 128, 0, stream>>>(
            link_state, path_state, link_to_path, Wp, Up, bip, bhp, n_paths);
        seg_sum_kernel<<<(n_links + 7)/8, 256, 0, stream>>>(
            path_state, offsets, entries, path_sum, n_links);
        link_kernel<<<(n_links + 127)/128, 128, 0, stream>>>(
            path_sum, link_state, Wl, Ul, bil, bhl, n_links);
    }
    readout_kernel<<<(n_links + 63)/64, 256, 0, stream>>>(
        link_state, W1, b1, W2, b2, W3, b3, (float*)d_out, n_links);
}

// Round 2
// 2350.498 us; speedup vs baseline: 1.6571x; 1.6571x over previous
//
#include <hip/hip_runtime.h>

#define DPDIM 32         // path/link state dim
#define GCOLS 96         // 3*DPDIM gate columns
#define PLEN 8
#define T_ITERS 8
#define RUNITS 256

// ---------------- fast activations (v_exp_f32 + v_rcp_f32) ----------------
__device__ __forceinline__ float fast_sigmoid(float a) {
    return __builtin_amdgcn_rcpf(1.0f + __expf(-a));
}
__device__ __forceinline__ float fast_tanh(float a) {
    // tanh(x) = 1 - 2/(1+e^{2x}); stable at both infinities
    return 1.0f - 2.0f * __builtin_amdgcn_rcpf(1.0f + __expf(2.0f * a));
}

#define ACC4(a0,a1,a2,a3, s, V) \
    a0 = fmaf((s), (V).x, a0); a1 = fmaf((s), (V).y, a1); \
    a2 = fmaf((s), (V).z, a2); a3 = fmaf((s), (V).w, a3);

#define ACC4F(A, s, V) \
    A.x = fmaf((s), (V).x, A.x); A.y = fmaf((s), (V).y, A.y); \
    A.z = fmaf((s), (V).z, A.z); A.w = fmaf((s), (V).w, A.w);

// ---------------- full GRU step (used by link_kernel only) ----------------
template<int STRIDE>
__device__ __forceinline__ void gru_step(
    float* __restrict__ h, const float* __restrict__ x,
    const float* __restrict__ sW, const float* __restrict__ sU,
    const float* __restrict__ sbi, const float* __restrict__ sbh,
    float* __restrict__ hl)
{
    for (int jb = 0; jb < 8; ++jb) {
        float az0=0.f,az1=0.f,az2=0.f,az3=0.f;
        float ar0=0.f,ar1=0.f,ar2=0.f,ar3=0.f;
        float ai0=0.f,ai1=0.f,ai2=0.f,ai3=0.f;
        float ah0=0.f,ah1=0.f,ah2=0.f,ah3=0.f;
        const float* wp = sW + jb*4;
        const float* up = sU + jb*4;
        #pragma unroll
        for (int k = 0; k < DPDIM; ++k) {
            const float xk = x[k], hk = h[k];
            const float4 WZ = *(const float4*)(wp + k*GCOLS);
            const float4 WR = *(const float4*)(wp + k*GCOLS + 32);
            const float4 WH = *(const float4*)(wp + k*GCOLS + 64);
            const float4 UZ = *(const float4*)(up + k*GCOLS);
            const float4 UR = *(const float4*)(up + k*GCOLS + 32);
            const float4 UH = *(const float4*)(up + k*GCOLS + 64);
            ACC4(az0,az1,az2,az3, xk, WZ); ACC4(az0,az1,az2,az3, hk, UZ);
            ACC4(ar0,ar1,ar2,ar3, xk, WR); ACC4(ar0,ar1,ar2,ar3, hk, UR);
            ACC4(ai0,ai1,ai2,ai3, xk, WH);
            ACC4(ah0,ah1,ah2,ah3, hk, UH);
        }
        const float4 BZI = *(const float4*)(sbi + jb*4);
        const float4 BRI = *(const float4*)(sbi + 32 + jb*4);
        const float4 BHI = *(const float4*)(sbi + 64 + jb*4);
        const float4 BZH = *(const float4*)(sbh + jb*4);
        const float4 BRH = *(const float4*)(sbh + 32 + jb*4);
        const float4 BHH = *(const float4*)(sbh + 64 + jb*4);
        float* hq = hl + (jb*4)*STRIDE;
        {
            float z = fast_sigmoid(az0 + BZI.x + BZH.x);
            float r = fast_sigmoid(ar0 + BRI.x + BRH.x);
            float c = fast_tanh(ai0 + BHI.x + r * (ah0 + BHH.x));
            float ho = hq[0*STRIDE]; hq[0*STRIDE] = z*ho + (1.f - z)*c;
        }
        {
            float z = fast_sigmoid(az1 + BZI.y + BZH.y);
            float r = fast_sigmoid(ar1 + BRI.y + BRH.y);
            float c = fast_tanh(ai1 + BHI.y + r * (ah1 + BHH.y));
            float ho = hq[1*STRIDE]; hq[1*STRIDE] = z*ho + (1.f - z)*c;
        }
        {
            float z = fast_sigmoid(az2 + BZI.z + BZH.z);
            float r = fast_sigmoid(ar2 + BRI.z + BRH.z);
            float c = fast_tanh(ai2 + BHI.z + r * (ah2 + BHH.z));
            float ho = hq[2*STRIDE]; hq[2*STRIDE] = z*ho + (1.f - z)*c;
        }
        {
            float z = fast_sigmoid(az3 + BZI.w + BZH.w);
            float r = fast_sigmoid(ar3 + BRI.w + BRH.w);
            float c = fast_tanh(ai3 + BHI.w + r * (ah3 + BHH.w));
            float ho = hq[3*STRIDE]; hq[3*STRIDE] = z*ho + (1.f - z)*c;
        }
    }
    #pragma unroll
    for (int j = 0; j < DPDIM; ++j) h[j] = hl[j*STRIDE];
}

// ---------------- init states ----------------
__global__ __launch_bounds__(256) void init_kernel(
    const float* __restrict__ traffic, const float* __restrict__ packets,
    const float* __restrict__ eqlam, const float* __restrict__ avgpkt,
    const float* __restrict__ capacity, const float* __restrict__ queues,
    float* __restrict__ path_state, float* __restrict__ link_state,
    int n_paths, int n_links)
{
    int i = blockIdx.x * 256 + threadIdx.x;
    if (i < n_paths) {
        float4* row = (float4*)(path_state + (size_t)i * DPDIM);
        row[0] = make_float4(traffic[i], packets[i], eqlam[i], avgpkt[i]);
        float4 z = make_float4(0.f, 0.f, 0.f, 0.f);
        #pragma unroll
        for (int k = 1; k < 8; ++k) row[k] = z;
    }
    if (i < n_links) {
        float4* row = (float4*)(link_state + (size_t)i * DPDIM);
        row[0] = make_float4(capacity[i], queues[i], 0.f, 0.f);
        float4 z = make_float4(0.f, 0.f, 0.f, 0.f);
        #pragma unroll
        for (int k = 1; k < 8; ++k) row[k] = z;
    }
}

// ---------------- CSR build ----------------
__global__ __launch_bounds__(256) void zero_counts_kernel(int* __restrict__ counts, int n) {
    int i = blockIdx.x * 256 + threadIdx.x;
    if (i < n) counts[i] = 0;
}
__global__ __launch_bounds__(256) void hist_kernel(
    const int* __restrict__ link_to_path, int* __restrict__ counts, int n) {
    int i = blockIdx.x * 256 + threadIdx.x;
    if (i < n) atomicAdd(&counts[link_to_path[i]], 1);
}
__global__ __launch_bounds__(1024) void scan_kernel(
    const int* __restrict__ counts, int* __restrict__ offsets,
    int* __restrict__ cursor, int n)
{
    __shared__ int s[1024];
    int t = threadIdx.x;
    int chunk = (n + 1023) >> 10;
    int lo = t * chunk;
    int hi = lo + chunk; if (hi > n) hi = n;
    int local = 0;
    for (int i = lo; i < hi; ++i) local += counts[i];
    s[t] = local;
    __syncthreads();
    for (int d = 1; d < 1024; d <<= 1) {
        int v = (t >= d) ? s[t - d] : 0;
        __syncthreads();
        s[t] += v;
        __syncthreads();
    }
    int base = (t > 0) ? s[t - 1] : 0;
    for (int i = lo; i < hi; ++i) {
        offsets[i] = base; cursor[i] = base; base += counts[i];
    }
    if (t == 1023) offsets[n] = s[1023];
}
__global__ __launch_bounds__(256) void fill_kernel(
    const int* __restrict__ link_to_path, int* __restrict__ cursor,
    int* __restrict__ entries, int n) {
    int e = blockIdx.x * 256 + threadIdx.x;
    if (e < n) {
        int l = link_to_path[e];
        int pos = atomicAdd(&cursor[l], 1);
        entries[pos] = e >> 3;   // path id (PLEN == 8)
    }
}

// ---------------- per-link input-gate precompute: Gi = ls@Wp + bip ---------
// Also records the keras-Masking flag (any nonzero element in the row).
__global__ __launch_bounds__(128) void gate_pre_kernel(
    const float* __restrict__ link_state,
    const float* __restrict__ Wp, const float* __restrict__ bip,
    float* __restrict__ Gi, int* __restrict__ nzf, int n_links)
{
    __shared__ __align__(16) float sW[DPDIM*GCOLS];
    __shared__ __align__(16) float sbi[GCOLS];
    int t = threadIdx.x;
    for (int i = t; i < DPDIM*GCOLS; i += 128) sW[i] = Wp[i];
    if (t < GCOLS) sbi[t] = bip[t];
    __syncthreads();
    int l = blockIdx.x * 128 + t;
    if (l >= n_links) return;
    float x[DPDIM];
    bool nz = false;
    const float4* row = (const float4*)(link_state + (size_t)l * DPDIM);
    #pragma unroll
    for (int k = 0; k < 8; ++k) {
        float4 v = row[k];
        x[4*k+0]=v.x; x[4*k+1]=v.y; x[4*k+2]=v.z; x[4*k+3]=v.w;
        nz = nz || (v.x != 0.f) || (v.y != 0.f) || (v.z != 0.f) || (v.w != 0.f);
    }
    float* G = Gi + (size_t)l * GCOLS;
    #pragma unroll 1
    for (int jb = 0; jb < 8; ++jb) {
        float4 az = {0,0,0,0}, ar = {0,0,0,0}, ah = {0,0,0,0};
        const float* wp = sW + jb*4;
        #pragma unroll
        for (int k = 0; k < DPDIM; ++k) {
            const float xk = x[k];
            const float4 WZ = *(const float4*)(wp + k*GCOLS);
            const float4 WR = *(const float4*)(wp + k*GCOLS + 32);
            const float4 WH = *(const float4*)(wp + k*GCOLS + 64);
            ACC4F(az, xk, WZ); ACC4F(ar, xk, WR); ACC4F(ah, xk, WH);
        }
        const float4 bz = *(const float4*)(sbi + jb*4);
        const float4 br = *(const float4*)(sbi + 32 + jb*4);
        const float4 bh = *(const float4*)(sbi + 64 + jb*4);
        *(float4*)(G + jb*4)      = make_float4(az.x+bz.x, az.y+bz.y, az.z+bz.z, az.w+bz.w);
        *(float4*)(G + 32 + jb*4) = make_float4(ar.x+br.x, ar.y+br.y, ar.z+br.z, ar.w+br.w);
        *(float4*)(G + 64 + jb*4) = make_float4(ah.x+bh.x, ah.y+bh.y, ah.z+bh.z, ah.w+bh.w);
    }
    nzf[l] = nz ? 1 : 0;
}

// ---------------- path GRU: 8 masked steps, x-gates precomputed ------------
__global__ __launch_bounds__(128, 1) void path_kernel(
    const float* __restrict__ Gi, const int* __restrict__ nzf,
    float* __restrict__ path_state, const int* __restrict__ link_to_path,
    const float* __restrict__ Up, const float* __restrict__ bhp, int n_paths)
{
    __shared__ __align__(16) float sU[DPDIM*GCOLS];   // 12 KB
    __shared__ __align__(16) float sbh[GCOLS];
    __shared__ float h_lds[DPDIM * 128];              // 16 KB, stride-128 cols
    int t = threadIdx.x;
    for (int i = t; i < DPDIM*GCOLS; i += 128) sU[i] = Up[i];
    if (t < GCOLS) sbh[t] = bhp[t];
    int p = blockIdx.x * 128 + t;
    bool act = p < n_paths;
    float h[DPDIM];
    if (act) {
        const float4* row = (const float4*)(path_state + (size_t)p * DPDIM);
        #pragma unroll
        for (int k = 0; k < 8; ++k) {
            float4 v = row[k];
            h[4*k+0]=v.x; h[4*k+1]=v.y; h[4*k+2]=v.z; h[4*k+3]=v.w;
        }
    } else {
        #pragma unroll
        for (int k = 0; k < DPDIM; ++k) h[k] = 0.f;
    }
    #pragma unroll
    for (int j = 0; j < DPDIM; ++j) h_lds[j*128 + t] = h[j];
    __syncthreads();

    #pragma unroll 1
    for (int s = 0; s < PLEN; ++s) {
        int l = act ? link_to_path[p*PLEN + s] : 0;
        bool nz = act && (nzf[l] != 0);
        const float* G = Gi + (size_t)l * GCOLS;
        #pragma unroll 1
        for (int jb = 0; jb < 8; ++jb) {
            // issue the 3 scattered gi loads early; consumed after the k-loop
            const float4 giz = *(const float4*)(G + jb*4);
            const float4 gir = *(const float4*)(G + 32 + jb*4);
            const float4 gih = *(const float4*)(G + 64 + jb*4);
            float4 az = {0,0,0,0}, ar = {0,0,0,0}, ah = {0,0,0,0};
            const float* up = sU + jb*4;
            #pragma unroll
            for (int k = 0; k < DPDIM; ++k) {
                const float hk = h[k];
                const float4 UZ = *(const float4*)(up + k*GCOLS);
                const float4 UR = *(const float4*)(up + k*GCOLS + 32);
                const float4 UH = *(const float4*)(up + k*GCOLS + 64);
                ACC4F(az, hk, UZ); ACC4F(ar, hk, UR); ACC4F(ah, hk, UH);
            }
            const float4 bhz = *(const float4*)(sbh + jb*4);
            const float4 bhr = *(const float4*)(sbh + 32 + jb*4);
            const float4 bhh = *(const float4*)(sbh + 64 + jb*4);
            float* hp = h_lds + (jb*4)*128 + t;
#define PWC(C, OFF) { \
            float zz = fast_sigmoid(giz.C + az.C + bhz.C); \
            float rr = fast_sigmoid(gir.C + ar.C + bhr.C); \
            float cc = fast_tanh(gih.C + rr * (ah.C + bhh.C)); \
            float ho = hp[OFF]; \
            hp[OFF] = nz ? (cc + zz * (ho - cc)) : ho; }
            PWC(x, 0) PWC(y, 128) PWC(z, 256) PWC(w, 384)
#undef PWC
        }
        #pragma unroll
        for (int j = 0; j < DPDIM; ++j) h[j] = h_lds[j*128 + t];
    }
    if (act) {
        float4* row = (float4*)(path_state + (size_t)p * DPDIM);
        #pragma unroll
        for (int k = 0; k < 8; ++k)
            row[k] = make_float4(h[4*k+0], h[4*k+1], h[4*k+2], h[4*k+3]);
    }
}

// ---------------- segment sum: path states -> per-link sums ----------------
__global__ __launch_bounds__(256) void seg_sum_kernel(
    const float* __restrict__ path_state, const int* __restrict__ offsets,
    const int* __restrict__ entries, float* __restrict__ path_sum, int n_links)
{
    int t = threadIdx.x;
    int d = t & 31, li = t >> 5;        // 8 links per block, 32 dims each
    int l = blockIdx.x * 8 + li;
    if (l >= n_links) return;
    int beg = offsets[l], end = offsets[l+1];
    float acc = 0.f;
    for (int q = beg; q < end; ++q) {
        int p = entries[q];
        acc += path_state[(size_t)p * DPDIM + d];
    }
    path_sum[(size_t)l * DPDIM + d] = acc;
}

// ---------------- link GRU: one step, x = path_sum -------------------------
__global__ __launch_bounds__(128, 1) void link_kernel(
    const float* __restrict__ path_sum, float* __restrict__ link_state,
    const float* __restrict__ Wl, const float* __restrict__ Ul,
    const float* __restrict__ bil, const float* __restrict__ bhl, int n_links)
{
    __shared__ __align__(16) float sW[DPDIM*GCOLS];
    __shared__ __align__(16) float sU[DPDIM*GCOLS];
    __shared__ __align__(16) float sbi[GCOLS];
    __shared__ __align__(16) float sbh[GCOLS];
    __shared__ float h_lds[DPDIM * 128];
    int t = threadIdx.x;
    for (int i = t; i < DPDIM*GCOLS; i += 128) { sW[i] = Wl[i]; sU[i] = Ul[i]; }
    for (int i = t; i < GCOLS; i += 128)       { sbi[i] = bil[i]; sbh[i] = bhl[i]; }
    int l = blockIdx.x * 128 + t;
    bool active = l < n_links;
    float h[DPDIM], x[DPDIM];
    if (active) {
        const float4* hrow = (const float4*)(link_state + (size_t)l * DPDIM);
        const float4* xrow = (const float4*)(path_sum + (size_t)l * DPDIM);
        #pragma unroll
        for (int k = 0; k < 8; ++k) {
            float4 v = hrow[k];
            h[4*k+0]=v.x; h[4*k+1]=v.y; h[4*k+2]=v.z; h[4*k+3]=v.w;
            float4 u = xrow[k];
            x[4*k+0]=u.x; x[4*k+1]=u.y; x[4*k+2]=u.z; x[4*k+3]=u.w;
        }
    } else {
        #pragma unroll
        for (int k = 0; k < DPDIM; ++k) { h[k] = 0.f; x[k] = 0.f; }
    }
    #pragma unroll
    for (int j = 0; j < DPDIM; ++j) h_lds[j*128 + t] = h[j];
    __syncthreads();
    if (active) {
        gru_step<128>(h, x, sW, sU, sbi, sbh, &h_lds[t]);
        float4* row = (float4*)(link_state + (size_t)l * DPDIM);
        #pragma unroll
        for (int k = 0; k < 8; ++k)
            row[k] = make_float4(h[4*k+0], h[4*k+1], h[4*k+2], h[4*k+3]);
    }
}

// ---------------- readout: relu(ls@W1+b1) -> relu(@W2+b2) -> @W3+b3 --------
__global__ __launch_bounds__(256) void readout_kernel(
    const float* __restrict__ link_state,
    const float* __restrict__ W1, const float* __restrict__ b1,
    const float* __restrict__ W2, const float* __restrict__ b2,
    const float* __restrict__ W3, const float* __restrict__ b3,
    float* __restrict__ out, int n_links)
{
    __shared__ __align__(16) float s_ls[64*DPDIM];   // 8 KB
    __shared__ float s_m[64*257];                    // 64.25 KB (r1, then r2*w3)
    __shared__ float s_part[256];
    __shared__ float s_w3[RUNITS];
    int t = threadIdx.x;
    int l0 = blockIdx.x * 64;
    int nl = n_links - l0; if (nl > 64) nl = 64;
    for (int i = t; i < nl*DPDIM; i += 256) s_ls[i] = link_state[(size_t)l0*DPDIM + i];
    s_w3[t] = W3[t];
    __syncthreads();
    // r1 = relu(ls @ W1 + b1) ; thread t owns column t
    float w1c[DPDIM];
    #pragma unroll
    for (int k = 0; k < DPDIM; ++k) w1c[k] = W1[k*RUNITS + t];
    float b1t = b1[t];
    for (int i = 0; i < nl; ++i) {
        float a = b1t;
        #pragma unroll
        for (int k = 0; k < DPDIM; ++k) a = fmaf(s_ls[i*DPDIM + k], w1c[k], a);
        s_m[i*257 + t] = fmaxf(a, 0.f);
    }
    __syncthreads();
    // r2 accum: acc[i] = sum_k r1[i][k] * W2[k][t]   (broadcast LDS reads)
    float acc[64];
    #pragma unroll
    for (int i = 0; i < 64; ++i) acc[i] = 0.f;
    for (int k = 0; k < RUNITS; ++k) {
        float w = W2[k*RUNITS + t];
        #pragma unroll
        for (int i = 0; i < 64; ++i) acc[i] = fmaf(s_m[i*257 + k], w, acc[i]);
    }
    __syncthreads();
    // store relu(acc+b2)*w3 back into s_m
    float b2t = b2[t];
    #pragma unroll
    for (int i = 0; i < 64; ++i)
        s_m[i*257 + t] = fmaxf(acc[i] + b2t, 0.f) * s_w3[t];
    __syncthreads();
    // reduce 256 cols per link: thread t handles link i=t>>2, quarter q=t&3
    {
        int i = t >> 2, q = t & 3;
        float ssum = 0.f;
        for (int j = q*64; j < q*64 + 64; ++j) ssum += s_m[i*257 + j];
        s_part[t] = ssum;
    }
    __syncthreads();
    if (t < nl)
        out[l0 + t] = b3[0] + s_part[t*4] + s_part[t*4+1] + s_part[t*4+2] + s_part[t*4+3];
}

// ---------------- launch ----------------
extern "C" void kernel_launch(void* const* d_in, const int* in_sizes, int n_in,
                              void* d_out, int out_size, void* d_ws, size_t ws_size,
                              hipStream_t stream)
{
    const float* traffic  = (const float*)d_in[0];
    const float* packets  = (const float*)d_in[1];
    const float* eqlam    = (const float*)d_in[2];
    const float* avgpkt   = (const float*)d_in[3];
    const float* capacity = (const float*)d_in[4];
    const float* queues   = (const float*)d_in[5];
    const int* link_to_path = (const int*)d_in[6];
    const float* Wp  = (const float*)d_in[13];
    const float* Up  = (const float*)d_in[14];
    const float* bip = (const float*)d_in[15];
    const float* bhp = (const float*)d_in[16];
    const float* Wl  = (const float*)d_in[17];
    const float* Ul  = (const float*)d_in[18];
    const float* bil = (const float*)d_in[19];
    const float* bhl = (const float*)d_in[20];
    const float* W1  = (const float*)d_in[21];
    const float* b1  = (const float*)d_in[22];
    const float* W2  = (const float*)d_in[23];
    const float* b2  = (const float*)d_in[24];
    const float* W3  = (const float*)d_in[25];
    const float* b3  = (const float*)d_in[26];
    const int n_paths = in_sizes[0];     // 100000
    const int n_links = in_sizes[4];     // 20000
    const int n_ent   = in_sizes[6];     // 800000

    char* ws = (char*)d_ws;
    size_t off = 0;
    auto salloc = [&](size_t bytes) -> void* {
        void* p = ws + off;
        off += (bytes + 255) & ~size_t(255);
        return p;
    };
    float* path_state = (float*)salloc((size_t)n_paths * DPDIM * 4);
    float* link_state = (float*)salloc((size_t)n_links * DPDIM * 4);
    // Gi (live: gate_pre -> path_kernel) and path_sum (live: seg_sum -> link_kernel)
    // never overlap in time; alias them to keep ws usage down.
    float* Gi         = (float*)salloc((size_t)n_links * GCOLS * 4);
    float* path_sum   = Gi;
    int* nzf     = (int*)salloc((size_t)n_links * 4);
    int* counts  = (int*)salloc((size_t)n_links * 4);
    int* offsets = (int*)salloc((size_t)(n_links + 1) * 4);
    int* cursor  = (int*)salloc((size_t)n_links * 4);
    int* entries = (int*)salloc((size_t)n_ent * 4);
    (void)ws_size; (void)n_in; (void)out_size;

    int gmax = ( (n_paths > n_links ? n_paths : n_links) + 255 ) / 256;
    zero_counts_kernel<<<(n_links + 255)/256, 256, 0, stream>>>(counts, n_links);
    init_kernel<<<gmax, 256, 0, stream>>>(traffic, packets, eqlam, avgpkt,
                                          capacity, queues, path_state, link_state,
                                          n_paths, n_links);
    hist_kernel<<<(n_ent + 255)/256, 256, 0, stream>>>(link_to_path, counts, n_ent);
    scan_kernel<<<1, 1024, 0, stream>>>(counts, offsets, cursor, n_links);
    fill_kernel<<<(n_ent + 255)/256, 256, 0, stream>>>(link_to_path, cursor, entries, n_ent);

    for (int it = 0; it < T_ITERS; ++it) {
        gate_pre_kernel<<<(n_links + 127)/128, 128, 0, stream>>>(
            link_state, Wp, bip, Gi, nzf, n_links);
        path_kernel<<<(n_paths + 127)/128, 128, 0, stream>>>(
            Gi, nzf, path_state, link_to_path, Up, bhp, n_paths);
        seg_sum_kernel<<<(n_links + 7)/8, 256, 0, stream>>>(
            path_state, offsets, entries, path_sum, n_links);
        link_kernel<<<(n_links + 127)/128, 128, 0, stream>>>(
            path_sum, link_state, Wl, Ul, bil, bhl, n_links);
    }
    readout_kernel<<<(n_links + 63)/64, 256, 0, stream>>>(
        link_state, W1, b1, W2, b2, W3, b3, (float*)d_out, n_links);
}

// Round 3
// 2058.989 us; speedup vs baseline: 1.8917x; 1.1416x over previous
//
#include <hip/hip_runtime.h>

#define DPDIM 32         // path/link state dim
#define GCOLS 96         // 3*DPDIM gate columns
#define PLEN 8
#define T_ITERS 8
#define RUNITS 256

// ---------------- fast activations (v_exp_f32 + v_rcp_f32) ----------------
__device__ __forceinline__ float fast_sigmoid(float a) {
    return __builtin_amdgcn_rcpf(1.0f + __expf(-a));
}
__device__ __forceinline__ float fast_tanh(float a) {
    // tanh(x) = 1 - 2/(1+e^{2x}); stable at both infinities
    return 1.0f - 2.0f * __builtin_amdgcn_rcpf(1.0f + __expf(2.0f * a));
}

#define ACC4(a0,a1,a2,a3, s, V) \
    a0 = fmaf((s), (V).x, a0); a1 = fmaf((s), (V).y, a1); \
    a2 = fmaf((s), (V).z, a2); a3 = fmaf((s), (V).w, a3);

#define ACC4F(A, s, V) \
    A.x = fmaf((s), (V).x, A.x); A.y = fmaf((s), (V).y, A.y); \
    A.z = fmaf((s), (V).z, A.z); A.w = fmaf((s), (V).w, A.w);

// ---------------- full GRU step (used by link_kernel only) ----------------
template<int STRIDE>
__device__ __forceinline__ void gru_step(
    float* __restrict__ h, const float* __restrict__ x,
    const float* __restrict__ sW, const float* __restrict__ sU,
    const float* __restrict__ sbi, const float* __restrict__ sbh,
    float* __restrict__ hl)
{
    for (int jb = 0; jb < 8; ++jb) {
        float az0=0.f,az1=0.f,az2=0.f,az3=0.f;
        float ar0=0.f,ar1=0.f,ar2=0.f,ar3=0.f;
        float ai0=0.f,ai1=0.f,ai2=0.f,ai3=0.f;
        float ah0=0.f,ah1=0.f,ah2=0.f,ah3=0.f;
        const float* wp = sW + jb*4;
        const float* up = sU + jb*4;
        #pragma unroll
        for (int k = 0; k < DPDIM; ++k) {
            const float xk = x[k], hk = h[k];
            const float4 WZ = *(const float4*)(wp + k*GCOLS);
            const float4 WR = *(const float4*)(wp + k*GCOLS + 32);
            const float4 WH = *(const float4*)(wp + k*GCOLS + 64);
            const float4 UZ = *(const float4*)(up + k*GCOLS);
            const float4 UR = *(const float4*)(up + k*GCOLS + 32);
            const float4 UH = *(const float4*)(up + k*GCOLS + 64);
            ACC4(az0,az1,az2,az3, xk, WZ); ACC4(az0,az1,az2,az3, hk, UZ);
            ACC4(ar0,ar1,ar2,ar3, xk, WR); ACC4(ar0,ar1,ar2,ar3, hk, UR);
            ACC4(ai0,ai1,ai2,ai3, xk, WH);
            ACC4(ah0,ah1,ah2,ah3, hk, UH);
        }
        const float4 BZI = *(const float4*)(sbi + jb*4);
        const float4 BRI = *(const float4*)(sbi + 32 + jb*4);
        const float4 BHI = *(const float4*)(sbi + 64 + jb*4);
        const float4 BZH = *(const float4*)(sbh + jb*4);
        const float4 BRH = *(const float4*)(sbh + 32 + jb*4);
        const float4 BHH = *(const float4*)(sbh + 64 + jb*4);
        float* hq = hl + (jb*4)*STRIDE;
        {
            float z = fast_sigmoid(az0 + BZI.x + BZH.x);
            float r = fast_sigmoid(ar0 + BRI.x + BRH.x);
            float c = fast_tanh(ai0 + BHI.x + r * (ah0 + BHH.x));
            float ho = hq[0*STRIDE]; hq[0*STRIDE] = z*ho + (1.f - z)*c;
        }
        {
            float z = fast_sigmoid(az1 + BZI.y + BZH.y);
            float r = fast_sigmoid(ar1 + BRI.y + BRH.y);
            float c = fast_tanh(ai1 + BHI.y + r * (ah1 + BHH.y));
            float ho = hq[1*STRIDE]; hq[1*STRIDE] = z*ho + (1.f - z)*c;
        }
        {
            float z = fast_sigmoid(az2 + BZI.z + BZH.z);
            float r = fast_sigmoid(ar2 + BRI.z + BRH.z);
            float c = fast_tanh(ai2 + BHI.z + r * (ah2 + BHH.z));
            float ho = hq[2*STRIDE]; hq[2*STRIDE] = z*ho + (1.f - z)*c;
        }
        {
            float z = fast_sigmoid(az3 + BZI.w + BZH.w);
            float r = fast_sigmoid(ar3 + BRI.w + BRH.w);
            float c = fast_tanh(ai3 + BHI.w + r * (ah3 + BHH.w));
            float ho = hq[3*STRIDE]; hq[3*STRIDE] = z*ho + (1.f - z)*c;
        }
    }
    #pragma unroll
    for (int j = 0; j < DPDIM; ++j) h[j] = hl[j*STRIDE];
}

// ---------------- init states ----------------
__global__ __launch_bounds__(256) void init_kernel(
    const float* __restrict__ traffic, const float* __restrict__ packets,
    const float* __restrict__ eqlam, const float* __restrict__ avgpkt,
    const float* __restrict__ capacity, const float* __restrict__ queues,
    float* __restrict__ path_state, float* __restrict__ link_state,
    int n_paths, int n_links)
{
    int i = blockIdx.x * 256 + threadIdx.x;
    if (i < n_paths) {
        float4* row = (float4*)(path_state + (size_t)i * DPDIM);
        row[0] = make_float4(traffic[i], packets[i], eqlam[i], avgpkt[i]);
        float4 z = make_float4(0.f, 0.f, 0.f, 0.f);
        #pragma unroll
        for (int k = 1; k < 8; ++k) row[k] = z;
    }
    if (i < n_links) {
        float4* row = (float4*)(link_state + (size_t)i * DPDIM);
        row[0] = make_float4(capacity[i], queues[i], 0.f, 0.f);
        float4 z = make_float4(0.f, 0.f, 0.f, 0.f);
        #pragma unroll
        for (int k = 1; k < 8; ++k) row[k] = z;
    }
}

// ---------------- weight transpose: Up[k][96] -> UpT[jb][k][12] ------------
// UpT[((jb*32)+k)*12 + idx], idx 0..3 = z cols jb*4+c, 4..7 = r, 8..11 = h
__global__ __launch_bounds__(256) void transpose_up_kernel(
    const float* __restrict__ Up, float* __restrict__ UpT)
{
    int i = blockIdx.x * 256 + threadIdx.x;
    if (i >= 8*32*12) return;
    int idx = i % 12;
    int k   = (i / 12) % 32;
    int jb  = i / (12*32);
    int gate = idx >> 2, c = idx & 3;
    UpT[i] = Up[k*GCOLS + gate*32 + jb*4 + c];
}

// ---------------- CSR build ----------------
__global__ __launch_bounds__(256) void zero_counts_kernel(int* __restrict__ counts, int n) {
    int i = blockIdx.x * 256 + threadIdx.x;
    if (i < n) counts[i] = 0;
}
__global__ __launch_bounds__(256) void hist_kernel(
    const int* __restrict__ link_to_path, int* __restrict__ counts, int n) {
    int i = blockIdx.x * 256 + threadIdx.x;
    if (i < n) atomicAdd(&counts[link_to_path[i]], 1);
}
__global__ __launch_bounds__(1024) void scan_kernel(
    const int* __restrict__ counts, int* __restrict__ offsets,
    int* __restrict__ cursor, int n)
{
    __shared__ int s[1024];
    int t = threadIdx.x;
    int chunk = (n + 1023) >> 10;
    int lo = t * chunk;
    int hi = lo + chunk; if (hi > n) hi = n;
    int local = 0;
    for (int i = lo; i < hi; ++i) local += counts[i];
    s[t] = local;
    __syncthreads();
    for (int d = 1; d < 1024; d <<= 1) {
        int v = (t >= d) ? s[t - d] : 0;
        __syncthreads();
        s[t] += v;
        __syncthreads();
    }
    int base = (t > 0) ? s[t - 1] : 0;
    for (int i = lo; i < hi; ++i) {
        offsets[i] = base; cursor[i] = base; base += counts[i];
    }
    if (t == 1023) offsets[n] = s[1023];
}
__global__ __launch_bounds__(256) void fill_kernel(
    const int* __restrict__ link_to_path, int* __restrict__ cursor,
    int* __restrict__ entries, int n) {
    int e = blockIdx.x * 256 + threadIdx.x;
    if (e < n) {
        int l = link_to_path[e];
        int pos = atomicAdd(&cursor[l], 1);
        entries[pos] = e >> 3;   // path id (PLEN == 8)
    }
}

// ---------------- per-link input-gate precompute ---------------------------
// Gi_z = x@Wz + biz + bhz ; Gi_r = x@Wr + bir + bhr ; Gi_h = x@Wh + bih
// (bhz/bhr folded here so path_kernel adds no biases; bhh stays separate
//  because the reference multiplies it by r.)
__global__ __launch_bounds__(128) void gate_pre_kernel(
    const float* __restrict__ link_state,
    const float* __restrict__ Wp, const float* __restrict__ bip,
    const float* __restrict__ bhp,
    float* __restrict__ Gi, int* __restrict__ nzf, int n_links)
{
    __shared__ __align__(16) float sW[DPDIM*GCOLS];
    __shared__ __align__(16) float sbi[GCOLS];
    __shared__ __align__(16) float sbh[GCOLS];
    int t = threadIdx.x;
    for (int i = t; i < DPDIM*GCOLS; i += 128) sW[i] = Wp[i];
    if (t < GCOLS) { sbi[t] = bip[t]; sbh[t] = bhp[t]; }
    __syncthreads();
    int l = blockIdx.x * 128 + t;
    if (l >= n_links) return;
    float x[DPDIM];
    bool nz = false;
    const float4* row = (const float4*)(link_state + (size_t)l * DPDIM);
    #pragma unroll
    for (int k = 0; k < 8; ++k) {
        float4 v = row[k];
        x[4*k+0]=v.x; x[4*k+1]=v.y; x[4*k+2]=v.z; x[4*k+3]=v.w;
        nz = nz || (v.x != 0.f) || (v.y != 0.f) || (v.z != 0.f) || (v.w != 0.f);
    }
    float* G = Gi + (size_t)l * GCOLS;
    #pragma unroll 1
    for (int jb = 0; jb < 8; ++jb) {
        float4 az = {0,0,0,0}, ar = {0,0,0,0}, ah = {0,0,0,0};
        const float* wp = sW + jb*4;
        #pragma unroll
        for (int k = 0; k < DPDIM; ++k) {
            const float xk = x[k];
            const float4 WZ = *(const float4*)(wp + k*GCOLS);
            const float4 WR = *(const float4*)(wp + k*GCOLS + 32);
            const float4 WH = *(const float4*)(wp + k*GCOLS + 64);
            ACC4F(az, xk, WZ); ACC4F(ar, xk, WR); ACC4F(ah, xk, WH);
        }
        const float4 bz = *(const float4*)(sbi + jb*4);
        const float4 br = *(const float4*)(sbi + 32 + jb*4);
        const float4 bh = *(const float4*)(sbi + 64 + jb*4);
        const float4 cz = *(const float4*)(sbh + jb*4);
        const float4 cr = *(const float4*)(sbh + 32 + jb*4);
        *(float4*)(G + jb*4)      = make_float4(az.x+bz.x+cz.x, az.y+bz.y+cz.y,
                                                az.z+bz.z+cz.z, az.w+bz.w+cz.w);
        *(float4*)(G + 32 + jb*4) = make_float4(ar.x+br.x+cr.x, ar.y+br.y+cr.y,
                                                ar.z+br.z+cr.z, ar.w+br.w+cr.w);
        *(float4*)(G + 64 + jb*4) = make_float4(ah.x+bh.x, ah.y+bh.y, ah.z+bh.z, ah.w+bh.w);
    }
    nzf[l] = nz ? 1 : 0;
}

// ---------------- path GRU: weights via uniform (scalar) loads -------------
// h lives in a per-thread LDS column, double-buffered; no barriers (each
// thread touches only its own column). Weight loads are wave-uniform ->
// SMEM/L1-broadcast, freeing the LDS pipe that bound round 2.
__global__ __launch_bounds__(64, 1) void path_kernel(
    const float* __restrict__ Gi, const int* __restrict__ nzf,
    float* __restrict__ path_state, const int* __restrict__ link_to_path,
    const float* __restrict__ UpT, const float* __restrict__ bhp, int n_paths)
{
    __shared__ float hbuf[2*DPDIM*64];    // 16 KB, [buf][k][lane]
    int t = threadIdx.x;
    int p = blockIdx.x * 64 + t;
    bool act = p < n_paths;
    int pp = act ? p : (n_paths - 1);
    {
        const float4* row = (const float4*)(path_state + (size_t)pp * DPDIM);
        #pragma unroll
        for (int k4 = 0; k4 < 8; ++k4) {
            float4 v = row[k4];
            hbuf[(4*k4+0)*64 + t] = v.x; hbuf[(4*k4+1)*64 + t] = v.y;
            hbuf[(4*k4+2)*64 + t] = v.z; hbuf[(4*k4+3)*64 + t] = v.w;
        }
    }
    int cur = 0;
    #pragma unroll 1
    for (int s = 0; s < PLEN; ++s) {
        int l = link_to_path[pp*PLEN + s];
        bool nz = act && (nzf[l] != 0);
        const float* G = Gi + (size_t)l * GCOLS;
        const float* hold = hbuf + cur*(DPDIM*64) + t;
        float* hnew = hbuf + (cur^1)*(DPDIM*64) + t;
        #pragma unroll 1
        for (int jb = 0; jb < 8; ++jb) {
            float4 az  = *(const float4*)(G + jb*4);
            float4 ar  = *(const float4*)(G + 32 + jb*4);
            float4 gih = *(const float4*)(G + 64 + jb*4);
            float4 ah  = *(const float4*)(bhp + 64 + jb*4);   // uniform
            const float* w = UpT + jb*(32*12);
            #pragma unroll 4
            for (int k = 0; k < DPDIM; ++k) {
                float hk = hold[k*64];
                const float4 wz = *(const float4*)(w);
                const float4 wr = *(const float4*)(w + 4);
                const float4 wh = *(const float4*)(w + 8);
                ACC4F(az, hk, wz); ACC4F(ar, hk, wr); ACC4F(ah, hk, wh);
                w += 12;
            }
#define PWC(C, j) { \
            float zz = fast_sigmoid(az.C); \
            float rr = fast_sigmoid(ar.C); \
            float cc = fast_tanh(gih.C + rr * ah.C); \
            float ho = hold[(jb*4+j)*64]; \
            hnew[(jb*4+j)*64] = nz ? (cc + zz * (ho - cc)) : ho; }
            PWC(x, 0) PWC(y, 1) PWC(z, 2) PWC(w, 3)
#undef PWC
        }
        cur ^= 1;
    }
    if (act) {
        const float* hf = hbuf + cur*(DPDIM*64) + t;
        float4* row = (float4*)(path_state + (size_t)p * DPDIM);
        #pragma unroll
        for (int k4 = 0; k4 < 8; ++k4)
            row[k4] = make_float4(hf[(4*k4+0)*64], hf[(4*k4+1)*64],
                                  hf[(4*k4+2)*64], hf[(4*k4+3)*64]);
    }
}

// ---------------- segment sum: path states -> per-link sums ----------------
__global__ __launch_bounds__(256) void seg_sum_kernel(
    const float* __restrict__ path_state, const int* __restrict__ offsets,
    const int* __restrict__ entries, float* __restrict__ path_sum, int n_links)
{
    int t = threadIdx.x;
    int d = t & 31, li = t >> 5;        // 8 links per block, 32 dims each
    int l = blockIdx.x * 8 + li;
    if (l >= n_links) return;
    int beg = offsets[l], end = offsets[l+1];
    float a0 = 0.f, a1 = 0.f, a2 = 0.f, a3 = 0.f;
    int q = beg;
    for (; q + 3 < end; q += 4) {
        int p0 = entries[q], p1 = entries[q+1], p2 = entries[q+2], p3 = entries[q+3];
        a0 += path_state[(size_t)p0 * DPDIM + d];
        a1 += path_state[(size_t)p1 * DPDIM + d];
        a2 += path_state[(size_t)p2 * DPDIM + d];
        a3 += path_state[(size_t)p3 * DPDIM + d];
    }
    for (; q < end; ++q)
        a0 += path_state[(size_t)entries[q] * DPDIM + d];
    path_sum[(size_t)l * DPDIM + d] = (a0 + a1) + (a2 + a3);
}

// ---------------- link GRU: one step, x = path_sum -------------------------
__global__ __launch_bounds__(128, 1) void link_kernel(
    const float* __restrict__ path_sum, float* __restrict__ link_state,
    const float* __restrict__ Wl, const float* __restrict__ Ul,
    const float* __restrict__ bil, const float* __restrict__ bhl, int n_links)
{
    __shared__ __align__(16) float sW[DPDIM*GCOLS];
    __shared__ __align__(16) float sU[DPDIM*GCOLS];
    __shared__ __align__(16) float sbi[GCOLS];
    __shared__ __align__(16) float sbh[GCOLS];
    __shared__ float h_lds[DPDIM * 128];
    int t = threadIdx.x;
    for (int i = t; i < DPDIM*GCOLS; i += 128) { sW[i] = Wl[i]; sU[i] = Ul[i]; }
    for (int i = t; i < GCOLS; i += 128)       { sbi[i] = bil[i]; sbh[i] = bhl[i]; }
    int l = blockIdx.x * 128 + t;
    bool active = l < n_links;
    float h[DPDIM], x[DPDIM];
    if (active) {
        const float4* hrow = (const float4*)(link_state + (size_t)l * DPDIM);
        const float4* xrow = (const float4*)(path_sum + (size_t)l * DPDIM);
        #pragma unroll
        for (int k = 0; k < 8; ++k) {
            float4 v = hrow[k];
            h[4*k+0]=v.x; h[4*k+1]=v.y; h[4*k+2]=v.z; h[4*k+3]=v.w;
            float4 u = xrow[k];
            x[4*k+0]=u.x; x[4*k+1]=u.y; x[4*k+2]=u.z; x[4*k+3]=u.w;
        }
    } else {
        #pragma unroll
        for (int k = 0; k < DPDIM; ++k) { h[k] = 0.f; x[k] = 0.f; }
    }
    #pragma unroll
    for (int j = 0; j < DPDIM; ++j) h_lds[j*128 + t] = h[j];
    __syncthreads();
    if (active) {
        gru_step<128>(h, x, sW, sU, sbi, sbh, &h_lds[t]);
        float4* row = (float4*)(link_state + (size_t)l * DPDIM);
        #pragma unroll
        for (int k = 0; k < 8; ++k)
            row[k] = make_float4(h[4*k+0], h[4*k+1], h[4*k+2], h[4*k+3]);
    }
}

// ---------------- readout: relu(ls@W1+b1) -> relu(@W2+b2) -> @W3+b3 --------
__global__ __launch_bounds__(256) void readout_kernel(
    const float* __restrict__ link_state,
    const float* __restrict__ W1, const float* __restrict__ b1,
    const float* __restrict__ W2, const float* __restrict__ b2,
    const float* __restrict__ W3, const float* __restrict__ b3,
    float* __restrict__ out, int n_links)
{
    __shared__ __align__(16) float s_ls[64*DPDIM];   // 8 KB
    __shared__ float s_m[64*257];                    // 64.25 KB (r1, then r2*w3)
    __shared__ float s_part[256];
    __shared__ float s_w3[RUNITS];
    int t = threadIdx.x;
    int l0 = blockIdx.x * 64;
    int nl = n_links - l0; if (nl > 64) nl = 64;
    for (int i = t; i < nl*DPDIM; i += 256) s_ls[i] = link_state[(size_t)l0*DPDIM + i];
    s_w3[t] = W3[t];
    __syncthreads();
    // r1 = relu(ls @ W1 + b1) ; thread t owns column t
    float w1c[DPDIM];
    #pragma unroll
    for (int k = 0; k < DPDIM; ++k) w1c[k] = W1[k*RUNITS + t];
    float b1t = b1[t];
    for (int i = 0; i < nl; ++i) {
        float a = b1t;
        #pragma unroll
        for (int k = 0; k < DPDIM; ++k) a = fmaf(s_ls[i*DPDIM + k], w1c[k], a);
        s_m[i*257 + t] = fmaxf(a, 0.f);
    }
    __syncthreads();
    // r2 accum: acc[i] = sum_k r1[i][k] * W2[k][t]   (broadcast LDS reads)
    float acc[64];
    #pragma unroll
    for (int i = 0; i < 64; ++i) acc[i] = 0.f;
    for (int k = 0; k < RUNITS; ++k) {
        float w = W2[k*RUNITS + t];
        #pragma unroll
        for (int i = 0; i < 64; ++i) acc[i] = fmaf(s_m[i*257 + k], w, acc[i]);
    }
    __syncthreads();
    // store relu(acc+b2)*w3 back into s_m
    float b2t = b2[t];
    #pragma unroll
    for (int i = 0; i < 64; ++i)
        s_m[i*257 + t] = fmaxf(acc[i] + b2t, 0.f) * s_w3[t];
    __syncthreads();
    // reduce 256 cols per link: thread t handles link i=t>>2, quarter q=t&3
    {
        int i = t >> 2, q = t & 3;
        float ssum = 0.f;
        for (int j = q*64; j < q*64 + 64; ++j) ssum += s_m[i*257 + j];
        s_part[t] = ssum;
    }
    __syncthreads();
    if (t < nl)
        out[l0 + t] = b3[0] + s_part[t*4] + s_part[t*4+1] + s_part[t*4+2] + s_part[t*4+3];
}

// ---------------- launch ----------------
extern "C" void kernel_launch(void* const* d_in, const int* in_sizes, int n_in,
                              void* d_out, int out_size, void* d_ws, size_t ws_size,
                              hipStream_t stream)
{
    const float* traffic  = (const float*)d_in[0];
    const float* packets  = (const float*)d_in[1];
    const float* eqlam    = (const float*)d_in[2];
    const float* avgpkt   = (const float*)d_in[3];
    const float* capacity = (const float*)d_in[4];
    const float* queues   = (const float*)d_in[5];
    const int* link_to_path = (const int*)d_in[6];
    const float* Wp  = (const float*)d_in[13];
    const float* Up  = (const float*)d_in[14];
    const float* bip = (const float*)d_in[15];
    const float* bhp = (const float*)d_in[16];
    const float* Wl  = (const float*)d_in[17];
    const float* Ul  = (const float*)d_in[18];
    const float* bil = (const float*)d_in[19];
    const float* bhl = (const float*)d_in[20];
    const float* W1  = (const float*)d_in[21];
    const float* b1  = (const float*)d_in[22];
    const float* W2  = (const float*)d_in[23];
    const float* b2  = (const float*)d_in[24];
    const float* W3  = (const float*)d_in[25];
    const float* b3  = (const float*)d_in[26];
    const int n_paths = in_sizes[0];     // 100000
    const int n_links = in_sizes[4];     // 20000
    const int n_ent   = in_sizes[6];     // 800000

    char* ws = (char*)d_ws;
    size_t off = 0;
    auto salloc = [&](size_t bytes) -> void* {
        void* p = ws + off;
        off += (bytes + 255) & ~size_t(255);
        return p;
    };
    float* path_state = (float*)salloc((size_t)n_paths * DPDIM * 4);
    float* link_state = (float*)salloc((size_t)n_links * DPDIM * 4);
    // Gi (live: gate_pre -> path_kernel) and path_sum (live: seg_sum -> link_kernel)
    // never overlap in time; alias them to keep ws usage down.
    float* Gi         = (float*)salloc((size_t)n_links * GCOLS * 4);
    float* path_sum   = Gi;
    float* UpT    = (float*)salloc((size_t)8 * 32 * 12 * 4);
    int* nzf     = (int*)salloc((size_t)n_links * 4);
    int* counts  = (int*)salloc((size_t)n_links * 4);
    int* offsets = (int*)salloc((size_t)(n_links + 1) * 4);
    int* cursor  = (int*)salloc((size_t)n_links * 4);
    int* entries = (int*)salloc((size_t)n_ent * 4);
    (void)ws_size; (void)n_in; (void)out_size;

    int gmax = ( (n_paths > n_links ? n_paths : n_links) + 255 ) / 256;
    zero_counts_kernel<<<(n_links + 255)/256, 256, 0, stream>>>(counts, n_links);
    init_kernel<<<gmax, 256, 0, stream>>>(traffic, packets, eqlam, avgpkt,
                                          capacity, queues, path_state, link_state,
                                          n_paths, n_links);
    transpose_up_kernel<<<(8*32*12 + 255)/256, 256, 0, stream>>>(Up, UpT);
    hist_kernel<<<(n_ent + 255)/256, 256, 0, stream>>>(link_to_path, counts, n_ent);
    scan_kernel<<<1, 1024, 0, stream>>>(counts, offsets, cursor, n_links);
    fill_kernel<<<(n_ent + 255)/256, 256, 0, stream>>>(link_to_path, cursor, entries, n_ent);

    for (int it = 0; it < T_ITERS; ++it) {
        gate_pre_kernel<<<(n_links + 127)/128, 128, 0, stream>>>(
            link_state, Wp, bip, bhp, Gi, nzf, n_links);
        path_kernel<<<(n_paths + 63)/64, 64, 0, stream>>>(
            Gi, nzf, path_state, link_to_path, UpT, bhp, n_paths);
        seg_sum_kernel<<<(n_links + 7)/8, 256, 0, stream>>>(
            path_state, offsets, entries, path_sum, n_links);
        link_kernel<<<(n_links + 127)/128, 128, 0, stream>>>(
            path_sum, link_state, Wl, Ul, bil, bhl, n_links);
    }
    readout_kernel<<<(n_links + 63)/64, 256, 0, stream>>>(
        link_state, W1, b1, W2, b2, W3, b3, (float*)d_out, n_links);
}